// Round 1
// baseline (39.793 us; speedup 1.0000x reference)
//
#include <hip/hip_runtime.h>
#include <hip/hip_bf16.h>
#include <math.h>

#define D 256
#define BATCH 2048
#define NREL 500
#define CURV_C 0.01f
#define SQRT_C 0.1f

__device__ __forceinline__ float artanh_f(float z) {
    z = fminf(fmaxf(z, -1.0f + 1e-7f), 1.0f - 1e-7f);
    return 0.5f * logf((1.0f + z) / (1.0f - z));
}

// block of 256 threads = 4 waves
__device__ __forceinline__ float block_reduce_sum(float v, float* sbuf) {
    #pragma unroll
    for (int off = 32; off > 0; off >>= 1) v += __shfl_down(v, off, 64);
    int lane = threadIdx.x & 63;
    int wid  = threadIdx.x >> 6;
    __syncthreads();            // protect sbuf from previous call's readers
    if (lane == 0) sbuf[wid] = v;
    __syncthreads();
    return sbuf[0] + sbuf[1] + sbuf[2] + sbuf[3];
}

// ---------- kernel A: rel_hyp = exp_map_zero(rel_embedding), r2 = ||rel_hyp||^2
__global__ __launch_bounds__(256) void rel_kernel(const float* __restrict__ rel,
                                                  float* __restrict__ rhyp,
                                                  float* __restrict__ r2out) {
    __shared__ float sbuf[4];
    int r = blockIdx.x, i = threadIdx.x;
    float v = rel[r * D + i];
    float n2 = block_reduce_sum(v * v, sbuf);
    float n  = fmaxf(sqrtf(n2), 1e-15f);
    float th = tanhf(SQRT_C * n);
    float f  = th / (SQRT_C * n);
    rhyp[r * D + i] = f * v;
    if (i == 0) r2out[r] = f * f * n2;
}

// ---------- kernel B: per-triplet query vector + q2 scalar
__global__ __launch_bounds__(256) void query_kernel(const float* __restrict__ ent,
                                                    const int* __restrict__ trip,
                                                    const float* __restrict__ grot,
                                                    const float* __restrict__ gref,
                                                    const float* __restrict__ attw,
                                                    float* __restrict__ query,
                                                    float* __restrict__ q2out) {
    __shared__ float sbuf[4];
    __shared__ float stan[D];
    int b = blockIdx.x, i = threadIdx.x;
    int s = trip[3 * b + 0];
    int o = trip[3 * b + 2];
    float se = ent[s * D + i];
    float oe = ent[o * D + i];

    float ns2 = block_reduce_sum(se * se, sbuf);
    float no2 = block_reduce_sum(oe * oe, sbuf);
    float ns = fmaxf(sqrtf(ns2), 1e-15f);
    float no = fmaxf(sqrtf(no2), 1e-15f);
    float fs = artanh_f(SQRT_C * ns) / (SQRT_C * ns);
    float fo = artanh_f(SQRT_C * no) / (SQRT_C * no);
    float st = fs * se;
    float ot = fo * oe;

    // attention scalar
    float adot = block_reduce_sum(st * attw[i] + ot * attw[D + i], sbuf);
    float a = 1.0f / (1.0f + expf(-adot));

    // givens rotation + reflection (pairs)
    stan[i] = st;
    __syncthreads();
    int j = i >> 1;
    float x1 = stan[2 * j], x2p = stan[2 * j + 1];
    float ca = cosf(grot[j]), sa = sinf(grot[j]);
    float cr = cosf(gref[j]), sr = sinf(gref[j]);
    float rot, refl;
    if ((i & 1) == 0) { rot = ca * x1 - sa * x2p; refl = cr * x1 + sr * x2p; }
    else              { rot = sa * x1 + ca * x2p; refl = sr * x1 - cr * x2p; }
    float mt = a * rot + (1.0f - a) * refl;

    // exp_map_zero(mixed_tan)
    float nm2 = block_reduce_sum(mt * mt, sbuf);
    float nm = fmaxf(sqrtf(nm2), 1e-15f);
    float thm = tanhf(SQRT_C * nm);
    float fm = thm / (SQRT_C * nm);
    float mh = fm * mt;                 // mixed_hyp element
    float x2v = fm * fm * nm2;          // ||mixed_hyp||^2

    // query = mobius_add(-mixed_hyp, o_emb)
    float xy = block_reduce_sum(-mh * oe, sbuf);
    float y2v = no2;
    const float c = CURV_C;
    float A  = 1.0f + 2.0f * c * xy + c * y2v;
    float Bf = 1.0f - c * x2v;
    float den = fmaxf(1.0f + 2.0f * c * xy + c * c * x2v * y2v, 1e-15f);
    float q = (A * (-mh) + Bf * oe) / den;
    query[b * D + i] = q;
    if (i == 0) {
        float num2 = A * A * x2v + 2.0f * A * Bf * xy + Bf * Bf * y2v;
        q2out[b] = num2 / (den * den);
    }
}

// ---------- kernel C: scores = -dist_sq(mobius_add(-query, rel_hyp)) + bias
// GEMM xy = dot(query[m], rel_hyp[n]); 64x64 tile, 4x4 microtile, K chunks of 32
#define KT 32
__global__ __launch_bounds__(256) void score_kernel(const float* __restrict__ Q,
                                                    const float* __restrict__ q2,
                                                    const float* __restrict__ H,
                                                    const float* __restrict__ r2,
                                                    const float* __restrict__ bias,
                                                    float* __restrict__ out) {
    __shared__ float As[64][36];
    __shared__ float Bs[64][36];
    const int t = threadIdx.x;
    const int tx = t & 15, ty = t >> 4;
    const int m0 = blockIdx.x * 64, n0 = blockIdx.y * 64;
    const int lr = t >> 2;           // 0..63: row within tile for loading
    const int lk = (t & 3) * 8;      // 0,8,16,24: k offset for loading

    float acc[4][4] = {{0.f}};

    for (int k0 = 0; k0 < D; k0 += KT) {
        const float4* pa = reinterpret_cast<const float4*>(&Q[(m0 + lr) * D + k0 + lk]);
        float4 a0 = pa[0], a1 = pa[1];
        float4 b0 = make_float4(0.f, 0.f, 0.f, 0.f), b1 = b0;
        int nrow = n0 + lr;
        if (nrow < NREL) {
            const float4* pb = reinterpret_cast<const float4*>(&H[nrow * D + k0 + lk]);
            b0 = pb[0]; b1 = pb[1];
        }
        __syncthreads();
        *reinterpret_cast<float4*>(&As[lr][lk])     = a0;
        *reinterpret_cast<float4*>(&As[lr][lk + 4]) = a1;
        *reinterpret_cast<float4*>(&Bs[lr][lk])     = b0;
        *reinterpret_cast<float4*>(&Bs[lr][lk + 4]) = b1;
        __syncthreads();
        #pragma unroll
        for (int kk = 0; kk < KT; kk += 4) {
            float4 av[4], bv[4];
            #pragma unroll
            for (int im = 0; im < 4; ++im)
                av[im] = *reinterpret_cast<const float4*>(&As[ty * 4 + im][kk]);
            #pragma unroll
            for (int in = 0; in < 4; ++in)
                bv[in] = *reinterpret_cast<const float4*>(&Bs[tx * 4 + in][kk]);
            #pragma unroll
            for (int im = 0; im < 4; ++im)
                #pragma unroll
                for (int in = 0; in < 4; ++in)
                    acc[im][in] += av[im].x * bv[in].x + av[im].y * bv[in].y
                                 + av[im].z * bv[in].z + av[im].w * bv[in].w;
        }
    }

    const float c = CURV_C;
    #pragma unroll
    for (int im = 0; im < 4; ++im) {
        int m = m0 + ty * 4 + im;
        float x2 = q2[m];
        float Bf = 1.0f - c * x2;
        #pragma unroll
        for (int in = 0; in < 4; ++in) {
            int n = n0 + tx * 4 + in;
            if (n < NREL) {
                float y2 = r2[n];
                float xy = -acc[im][in];          // x = -query
                float A  = 1.0f + 2.0f * c * xy + c * y2;
                float den = fmaxf(1.0f + 2.0f * c * xy + c * c * x2 * y2, 1e-15f);
                float num2 = A * A * x2 + 2.0f * A * Bf * xy + Bf * Bf * y2;
                out[m * NREL + n] = bias[n] - num2 / (den * den);
            }
        }
    }
}

extern "C" void kernel_launch(void* const* d_in, const int* in_sizes, int n_in,
                              void* d_out, int out_size, void* d_ws, size_t ws_size,
                              hipStream_t stream) {
    const float* ent  = (const float*)d_in[0];   // 20000 x 256
    const float* rel  = (const float*)d_in[1];   // 500 x 256
    const int*   trip = (const int*)d_in[2];     // 2048 x 3
    const float* grot = (const float*)d_in[3];   // 128
    const float* gref = (const float*)d_in[4];   // 128
    const float* attw = (const float*)d_in[5];   // 512
    const float* bias = (const float*)d_in[6];   // 500
    float* out = (float*)d_out;                  // 2048 x 500

    char* ws = (char*)d_ws;
    float* query = (float*)(ws);                               // 2048*256
    float* q2    = (float*)(ws + (size_t)BATCH * D * 4);       // 2048
    float* rhyp  = (float*)(ws + (size_t)BATCH * D * 4 + 8192);        // 500*256
    float* r2    = (float*)(ws + (size_t)BATCH * D * 4 + 8192 + (size_t)NREL * D * 4); // 500

    rel_kernel<<<NREL, 256, 0, stream>>>(rel, rhyp, r2);
    query_kernel<<<BATCH, 256, 0, stream>>>(ent, trip, grot, gref, attw, query, q2);
    dim3 grid(BATCH / 64, (NREL + 63) / 64);
    score_kernel<<<grid, 256, 0, stream>>>(query, q2, rhyp, r2, bias, out);
}

// Round 2
// 25.657 us; speedup vs baseline: 1.5509x; 1.5509x over previous
//
#include <hip/hip_runtime.h>
#include <hip/hip_bf16.h>
#include <math.h>

#define D 256
#define BATCH 2048
#define NREL 500
#define CURV_C 0.01f
#define SQRT_C 0.1f

__device__ __forceinline__ float wave_reduce(float v) {
    #pragma unroll
    for (int off = 1; off < 64; off <<= 1) v += __shfl_xor(v, off, 64);
    return v;
}

__device__ __forceinline__ float dot4(float4 a, float4 b) {
    return a.x * b.x + a.y * b.y + a.z * b.z + a.w * b.w;
}

__device__ __forceinline__ float artanh_f(float z) {
    z = fminf(fmaxf(z, -1.0f + 1e-7f), 1.0f - 1e-7f);
    return 0.5f * logf((1.0f + z) / (1.0f - z));
}

// ---------------- prep: wave-per-row, no barriers ----------------
// waves [0, NREL)            -> rel_hyp + r2
// waves [NREL, NREL+BATCH)   -> query + q2
__global__ __launch_bounds__(256) void prep_kernel(
    const float* __restrict__ ent, const float* __restrict__ rel,
    const int* __restrict__ trip,
    const float* __restrict__ grot, const float* __restrict__ gref,
    const float* __restrict__ attw,
    float* __restrict__ query, float* __restrict__ q2out,
    float* __restrict__ rhyp, float* __restrict__ r2out)
{
    const int w = blockIdx.x * 4 + (threadIdx.x >> 6);
    const int l = threadIdx.x & 63;

    if (w < NREL) {
        const int r = w;
        float4 v = *(const float4*)&rel[(size_t)r * D + 4 * l];
        float n2 = wave_reduce(dot4(v, v));
        float n = fmaxf(sqrtf(n2), 1e-15f);
        float f = tanhf(SQRT_C * n) / (SQRT_C * n);
        float4 hv = make_float4(f * v.x, f * v.y, f * v.z, f * v.w);
        *(float4*)&rhyp[(size_t)r * D + 4 * l] = hv;
        if (l == 0) r2out[r] = f * f * n2;
    } else if (w < NREL + BATCH) {
        const int b = w - NREL;
        const int s = trip[3 * b + 0];
        const int o = trip[3 * b + 2];
        float4 se = *(const float4*)&ent[(size_t)s * D + 4 * l];
        float4 oe = *(const float4*)&ent[(size_t)o * D + 4 * l];

        float ns2 = wave_reduce(dot4(se, se));
        float no2 = wave_reduce(dot4(oe, oe));
        float ns = fmaxf(sqrtf(ns2), 1e-15f);
        float no = fmaxf(sqrtf(no2), 1e-15f);
        float fs = artanh_f(SQRT_C * ns) / (SQRT_C * ns);
        float fo = artanh_f(SQRT_C * no) / (SQRT_C * no);
        float4 st = make_float4(fs * se.x, fs * se.y, fs * se.z, fs * se.w);
        float4 ot = make_float4(fo * oe.x, fo * oe.y, fo * oe.z, fo * oe.w);

        float4 wa = *(const float4*)&attw[4 * l];
        float4 wb = *(const float4*)&attw[D + 4 * l];
        float adot = wave_reduce(dot4(st, wa) + dot4(ot, wb));
        float a = 1.0f / (1.0f + expf(-adot));

        // Givens pairs are lane-local: (x,y) angle 2l, (z,w) angle 2l+1
        float2 ar = ((const float2*)grot)[l];
        float2 af = ((const float2*)gref)[l];
        float ca0 = cosf(ar.x), sa0 = sinf(ar.x);
        float ca1 = cosf(ar.y), sa1 = sinf(ar.y);
        float cr0 = cosf(af.x), sr0 = sinf(af.x);
        float cr1 = cosf(af.y), sr1 = sinf(af.y);

        float4 rot = make_float4(ca0 * st.x - sa0 * st.y, sa0 * st.x + ca0 * st.y,
                                 ca1 * st.z - sa1 * st.w, sa1 * st.z + ca1 * st.w);
        float4 rfl = make_float4(cr0 * st.x + sr0 * st.y, sr0 * st.x - cr0 * st.y,
                                 cr1 * st.z + sr1 * st.w, sr1 * st.z - cr1 * st.w);
        float ia = 1.0f - a;
        float4 mt = make_float4(a * rot.x + ia * rfl.x, a * rot.y + ia * rfl.y,
                                a * rot.z + ia * rfl.z, a * rot.w + ia * rfl.w);

        float nm2 = wave_reduce(dot4(mt, mt));
        float nm = fmaxf(sqrtf(nm2), 1e-15f);
        float fm = tanhf(SQRT_C * nm) / (SQRT_C * nm);
        float4 mh = make_float4(fm * mt.x, fm * mt.y, fm * mt.z, fm * mt.w);
        float x2v = fm * fm * nm2;

        float xy = wave_reduce(-dot4(mh, oe));
        const float c = CURV_C;
        float A  = 1.0f + 2.0f * c * xy + c * no2;
        float Bf = 1.0f - c * x2v;
        float den = fmaxf(1.0f + 2.0f * c * xy + c * c * x2v * no2, 1e-15f);
        float inv = 1.0f / den;
        float4 q = make_float4((A * -mh.x + Bf * oe.x) * inv,
                               (A * -mh.y + Bf * oe.y) * inv,
                               (A * -mh.z + Bf * oe.z) * inv,
                               (A * -mh.w + Bf * oe.w) * inv);
        *(float4*)&query[(size_t)b * D + 4 * l] = q;
        if (l == 0) {
            float num2 = A * A * x2v + 2.0f * A * Bf * xy + Bf * Bf * no2;
            q2out[b] = num2 * inv * inv;
        }
    }
}

// ---------------- score: 64x64 tile, k-major LDS, double-buffered ----------------
#define KT 32
__global__ __launch_bounds__(256) void score_kernel(
    const float* __restrict__ Q, const float* __restrict__ q2,
    const float* __restrict__ H, const float* __restrict__ r2,
    const float* __restrict__ bias, float* __restrict__ out)
{
    __shared__ float At[2][KT][68];   // [buf][k][m]
    __shared__ float Bt[2][KT][68];   // [buf][k][n]

    const int t = threadIdx.x;
    const int tx = t & 15;            // n-group
    const int ty = t >> 4;            // m-group (0..15)
    const int m0 = blockIdx.x * 64, n0 = blockIdx.y * 64;

    const int lr  = t & 63;           // row within tile for staging
    const int klo = (t >> 6) * 8;     // k-offset quarter for staging

    const float* Arow = &Q[(size_t)(m0 + lr) * D + klo];
    const bool bvalid = (n0 + lr) < NREL;
    const float* Brow = bvalid ? &H[(size_t)(n0 + lr) * D + klo] : &H[0];

    float acc[4][4] = {{0.f}};

    float4 a0 = *(const float4*)(Arow + 0);
    float4 a1 = *(const float4*)(Arow + 4);
    float4 b0 = make_float4(0.f, 0.f, 0.f, 0.f), b1 = b0;
    if (bvalid) { b0 = *(const float4*)(Brow + 0); b1 = *(const float4*)(Brow + 4); }
    #pragma unroll
    for (int e = 0; e < 4; ++e) {
        At[0][klo + e][lr] = (&a0.x)[e]; At[0][klo + 4 + e][lr] = (&a1.x)[e];
        Bt[0][klo + e][lr] = (&b0.x)[e]; Bt[0][klo + 4 + e][lr] = (&b1.x)[e];
    }
    __syncthreads();

    const int NCH = D / KT;           // 8 chunks
    #pragma unroll 1
    for (int ch = 0; ch < NCH; ++ch) {
        const int cur = ch & 1, nxt = cur ^ 1;
        float4 na0, na1, nb0, nb1;
        if (ch + 1 < NCH) {
            const int k0 = (ch + 1) * KT;
            na0 = *(const float4*)(Arow + k0);
            na1 = *(const float4*)(Arow + k0 + 4);
            nb0 = make_float4(0.f, 0.f, 0.f, 0.f); nb1 = nb0;
            if (bvalid) { nb0 = *(const float4*)(Brow + k0); nb1 = *(const float4*)(Brow + k0 + 4); }
        }
        #pragma unroll
        for (int kk = 0; kk < KT; ++kk) {
            float4 av = *(const float4*)&At[cur][kk][4 * ty];
            float4 bv = *(const float4*)&Bt[cur][kk][4 * tx];
            acc[0][0] += av.x * bv.x; acc[0][1] += av.x * bv.y;
            acc[0][2] += av.x * bv.z; acc[0][3] += av.x * bv.w;
            acc[1][0] += av.y * bv.x; acc[1][1] += av.y * bv.y;
            acc[1][2] += av.y * bv.z; acc[1][3] += av.y * bv.w;
            acc[2][0] += av.z * bv.x; acc[2][1] += av.z * bv.y;
            acc[2][2] += av.z * bv.z; acc[2][3] += av.z * bv.w;
            acc[3][0] += av.w * bv.x; acc[3][1] += av.w * bv.y;
            acc[3][2] += av.w * bv.z; acc[3][3] += av.w * bv.w;
        }
        if (ch + 1 < NCH) {
            #pragma unroll
            for (int e = 0; e < 4; ++e) {
                At[nxt][klo + e][lr] = (&na0.x)[e]; At[nxt][klo + 4 + e][lr] = (&na1.x)[e];
                Bt[nxt][klo + e][lr] = (&nb0.x)[e]; Bt[nxt][klo + 4 + e][lr] = (&nb1.x)[e];
            }
            __syncthreads();
        }
    }

    const float c = CURV_C;
    #pragma unroll
    for (int im = 0; im < 4; ++im) {
        const int m = m0 + 4 * ty + im;
        const float x2 = q2[m];
        const float Bf = 1.0f - c * x2;
        const int nb = n0 + 4 * tx;
        if (nb < NREL) {
            float4 res;
            #pragma unroll
            for (int in = 0; in < 4; ++in) {
                const int n = nb + in;
                const float y2 = r2[n];
                const float xy = -acc[im][in];
                const float A  = 1.0f + 2.0f * c * xy + c * y2;
                const float den = fmaxf(1.0f + 2.0f * c * xy + c * c * x2 * y2, 1e-15f);
                const float num2 = A * A * x2 + 2.0f * A * Bf * xy + Bf * Bf * y2;
                (&res.x)[in] = bias[n] - num2 / (den * den);
            }
            *(float4*)&out[(size_t)m * NREL + nb] = res;
        }
    }
}

extern "C" void kernel_launch(void* const* d_in, const int* in_sizes, int n_in,
                              void* d_out, int out_size, void* d_ws, size_t ws_size,
                              hipStream_t stream) {
    const float* ent  = (const float*)d_in[0];   // 20000 x 256
    const float* rel  = (const float*)d_in[1];   // 500 x 256
    const int*   trip = (const int*)d_in[2];     // 2048 x 3
    const float* grot = (const float*)d_in[3];   // 128
    const float* gref = (const float*)d_in[4];   // 128
    const float* attw = (const float*)d_in[5];   // 512
    const float* bias = (const float*)d_in[6];   // 500
    float* out = (float*)d_out;                  // 2048 x 500

    char* ws = (char*)d_ws;
    float* query = (float*)(ws);                                        // 2048*256
    float* q2    = (float*)(ws + (size_t)BATCH * D * 4);                // 2048
    float* rhyp  = (float*)(ws + (size_t)BATCH * D * 4 + 8192);         // 500*256
    float* r2    = (float*)(ws + (size_t)BATCH * D * 4 + 8192 + (size_t)NREL * D * 4); // 500

    const int nwaves = NREL + BATCH;            // 2548
    prep_kernel<<<(nwaves + 3) / 4, 256, 0, stream>>>(ent, rel, trip, grot, gref,
                                                      attw, query, q2, rhyp, r2);
    dim3 grid(BATCH / 64, (NREL + 63) / 64);
    score_kernel<<<grid, 256, 0, stream>>>(query, q2, rhyp, r2, bias, out);
}

// Round 3
// 21.337 us; speedup vs baseline: 1.8650x; 1.2025x over previous
//
#include <hip/hip_runtime.h>
#include <hip/hip_bf16.h>
#include <math.h>

#define D 256
#define BATCH 2048
#define NREL 500
#define NRELP 512
#define CURV_C 0.01f
#define SQRT_C 0.1f

typedef __attribute__((ext_vector_type(8))) short s16x8;
typedef __attribute__((ext_vector_type(4))) float f32x4;

__device__ __forceinline__ float wave_reduce(float v) {
    #pragma unroll
    for (int off = 1; off < 64; off <<= 1) v += __shfl_xor(v, off, 64);
    return v;
}

__device__ __forceinline__ float dot4(float4 a, float4 b) {
    return a.x * b.x + a.y * b.y + a.z * b.z + a.w * b.w;
}

__device__ __forceinline__ float artanh_f(float z) {
    z = fminf(fmaxf(z, -1.0f + 1e-7f), 1.0f - 1e-7f);
    return 0.5f * logf((1.0f + z) / (1.0f - z));
}

__device__ __forceinline__ unsigned short f2bf(float x) {
    union { float f; unsigned int u; } c; c.f = x;
    unsigned int r = (c.u + 0x7fffu + ((c.u >> 16) & 1u)) >> 16;
    return (unsigned short)r;
}
__device__ __forceinline__ float bf2f(unsigned short h) {
    union { unsigned int u; float f; } c; c.u = ((unsigned int)h) << 16;
    return c.f;
}

// split float4 into bf16 hi + bf16 lo (residual), store 8B each
__device__ __forceinline__ void store_hilo(unsigned short* ph, unsigned short* pl, float4 v) {
    ushort4 h, lo;
    #pragma unroll
    for (int e = 0; e < 4; ++e) {
        float x = (&v.x)[e];
        unsigned short hb = f2bf(x);
        float hf = bf2f(hb);
        (&h.x)[e] = hb;
        (&lo.x)[e] = f2bf(x - hf);
    }
    *(ushort4*)ph = h;
    *(ushort4*)pl = lo;
}

// ---------------- prep: wave-per-row, no barriers ----------------
// waves [0, NRELP)           -> Hh/Hl + r2  (rows >= NREL zero-padded)
// waves [NRELP, NRELP+BATCH) -> Qh/Ql + q2
__global__ __launch_bounds__(256) void prep_kernel(
    const float* __restrict__ ent, const float* __restrict__ rel,
    const int* __restrict__ trip,
    const float* __restrict__ grot, const float* __restrict__ gref,
    const float* __restrict__ attw,
    unsigned short* __restrict__ Qh, unsigned short* __restrict__ Ql,
    float* __restrict__ q2out,
    unsigned short* __restrict__ Hh, unsigned short* __restrict__ Hl,
    float* __restrict__ r2out)
{
    const int w = blockIdx.x * 4 + (threadIdx.x >> 6);
    const int l = threadIdx.x & 63;

    if (w < NRELP) {
        const int r = w;
        float4 v = make_float4(0.f, 0.f, 0.f, 0.f);
        if (r < NREL) v = *(const float4*)&rel[(size_t)r * D + 4 * l];
        float n2 = wave_reduce(dot4(v, v));
        float n = fmaxf(sqrtf(n2), 1e-15f);
        float f = tanhf(SQRT_C * n) / (SQRT_C * n);
        float4 hv = make_float4(f * v.x, f * v.y, f * v.z, f * v.w);
        store_hilo(&Hh[(size_t)r * D + 4 * l], &Hl[(size_t)r * D + 4 * l], hv);
        if (l == 0) r2out[r] = f * f * n2;
    } else if (w < NRELP + BATCH) {
        const int b = w - NRELP;
        const int s = trip[3 * b + 0];
        const int o = trip[3 * b + 2];
        float4 se = *(const float4*)&ent[(size_t)s * D + 4 * l];
        float4 oe = *(const float4*)&ent[(size_t)o * D + 4 * l];

        float ns2 = wave_reduce(dot4(se, se));
        float no2 = wave_reduce(dot4(oe, oe));
        float ns = fmaxf(sqrtf(ns2), 1e-15f);
        float no = fmaxf(sqrtf(no2), 1e-15f);
        float fs = artanh_f(SQRT_C * ns) / (SQRT_C * ns);
        float fo = artanh_f(SQRT_C * no) / (SQRT_C * no);
        float4 st = make_float4(fs * se.x, fs * se.y, fs * se.z, fs * se.w);
        float4 ot = make_float4(fo * oe.x, fo * oe.y, fo * oe.z, fo * oe.w);

        float4 wa = *(const float4*)&attw[4 * l];
        float4 wb = *(const float4*)&attw[D + 4 * l];
        float adot = wave_reduce(dot4(st, wa) + dot4(ot, wb));
        float a = 1.0f / (1.0f + expf(-adot));

        float2 ar = ((const float2*)grot)[l];
        float2 af = ((const float2*)gref)[l];
        float ca0 = cosf(ar.x), sa0 = sinf(ar.x);
        float ca1 = cosf(ar.y), sa1 = sinf(ar.y);
        float cr0 = cosf(af.x), sr0 = sinf(af.x);
        float cr1 = cosf(af.y), sr1 = sinf(af.y);

        float4 rot = make_float4(ca0 * st.x - sa0 * st.y, sa0 * st.x + ca0 * st.y,
                                 ca1 * st.z - sa1 * st.w, sa1 * st.z + ca1 * st.w);
        float4 rfl = make_float4(cr0 * st.x + sr0 * st.y, sr0 * st.x - cr0 * st.y,
                                 cr1 * st.z + sr1 * st.w, sr1 * st.z - cr1 * st.w);
        float ia = 1.0f - a;
        float4 mt = make_float4(a * rot.x + ia * rfl.x, a * rot.y + ia * rfl.y,
                                a * rot.z + ia * rfl.z, a * rot.w + ia * rfl.w);

        float nm2 = wave_reduce(dot4(mt, mt));
        float nm = fmaxf(sqrtf(nm2), 1e-15f);
        float fm = tanhf(SQRT_C * nm) / (SQRT_C * nm);
        float4 mh = make_float4(fm * mt.x, fm * mt.y, fm * mt.z, fm * mt.w);
        float x2v = fm * fm * nm2;

        float xy = wave_reduce(-dot4(mh, oe));
        const float c = CURV_C;
        float A  = 1.0f + 2.0f * c * xy + c * no2;
        float Bf = 1.0f - c * x2v;
        float den = fmaxf(1.0f + 2.0f * c * xy + c * c * x2v * no2, 1e-15f);
        float inv = 1.0f / den;
        float4 q = make_float4((A * -mh.x + Bf * oe.x) * inv,
                               (A * -mh.y + Bf * oe.y) * inv,
                               (A * -mh.z + Bf * oe.z) * inv,
                               (A * -mh.w + Bf * oe.w) * inv);
        store_hilo(&Qh[(size_t)b * D + 4 * l], &Ql[(size_t)b * D + 4 * l], q);
        if (l == 0) {
            float num2 = A * A * x2v + 2.0f * A * Bf * xy + Bf * Bf * no2;
            q2out[b] = num2 * inv * inv;
        }
    }
}

// ---------------- score: 64x64 tile, MFMA bf16 hi/lo, full-K LDS stage ----------------
// LDS: Ah @0, Al @32768, Bh @65536, Bl @98304 ; each [64 rows][256 k] bf16 (512B/row)
// swizzle: byte_in_row ^= (row&7)<<4  (16B-chunk granularity)
__global__ __launch_bounds__(256) void score_kernel(
    const unsigned short* __restrict__ Qh, const unsigned short* __restrict__ Ql,
    const float* __restrict__ q2,
    const unsigned short* __restrict__ Hh, const unsigned short* __restrict__ Hl,
    const float* __restrict__ r2,
    const float* __restrict__ bias, float* __restrict__ out)
{
    __shared__ __align__(16) unsigned char lds[131072];
    const int t = threadIdx.x;
    const int m0 = blockIdx.x * 64, n0 = blockIdx.y * 64;

    // ---- stage all four 32KB tiles (reg-staged, swizzled ds_write_b128)
    {
        const int row = t >> 2;          // 0..63
        const int cg  = t & 3;           // 0..3: which 128B quarter of the row
        const unsigned int rbase = row * 512;
        const unsigned int rsw   = (row & 7) << 4;
        const size_t goffA = (size_t)(m0 + row) * D + cg * 64;   // elems
        const size_t goffB = (size_t)(n0 + row) * D + cg * 64;
        #pragma unroll
        for (int j = 0; j < 8; ++j) {
            const unsigned int c = cg * 8 + j;                   // 16B chunk idx 0..31
            const unsigned int off = rbase + ((c << 4) ^ rsw);
            *(float4*)(lds + off)          = *(const float4*)(Qh + goffA + j * 8);
            *(float4*)(lds + 32768 + off)  = *(const float4*)(Ql + goffA + j * 8);
            *(float4*)(lds + 65536 + off)  = *(const float4*)(Hh + goffB + j * 8);
            *(float4*)(lds + 98304 + off)  = *(const float4*)(Hl + goffB + j * 8);
        }
    }
    __syncthreads();

    // ---- MFMA: each wave owns a 64(m) x 16(n) strip
    const int wv = t >> 6;               // 0..3 -> n strip
    const int l  = t & 63;
    const int lr = l & 15;               // fragment row/col
    const int lk = l >> 4;               // fragment k-chunk 0..3
    const unsigned int sw = (lr & 7) << 4;   // same for all rows used by this lane

    f32x4 acc[4];
    #pragma unroll
    for (int mi = 0; mi < 4; ++mi) acc[mi] = (f32x4){0.f, 0.f, 0.f, 0.f};

    const unsigned int browB = wv * 16 + lr;
    const unsigned int bbase = browB * 512;
    #pragma unroll
    for (int ks = 0; ks < 8; ++ks) {
        const unsigned int c = ks * 4 + lk;
        const unsigned int boff = bbase + ((c << 4) ^ sw);
        s16x8 bh = *(const s16x8*)(lds + 65536 + boff);
        s16x8 bl = *(const s16x8*)(lds + 98304 + boff);
        #pragma unroll
        for (int mi = 0; mi < 4; ++mi) {
            const unsigned int aoff = (mi * 16 + lr) * 512 + ((c << 4) ^ sw);
            s16x8 ah = *(const s16x8*)(lds + aoff);
            s16x8 al = *(const s16x8*)(lds + 32768 + aoff);
            acc[mi] = __builtin_amdgcn_mfma_f32_16x16x32_bf16(ah, bh, acc[mi], 0, 0, 0);
            acc[mi] = __builtin_amdgcn_mfma_f32_16x16x32_bf16(ah, bl, acc[mi], 0, 0, 0);
            acc[mi] = __builtin_amdgcn_mfma_f32_16x16x32_bf16(al, bh, acc[mi], 0, 0, 0);
        }
    }

    // ---- epilogue: C frag layout col=lane&15 (n), row=(lane>>4)*4+reg (m)
    const int n = n0 + wv * 16 + lr;
    const bool nok = (n < NREL);
    float y2v = 0.f, biasv = 0.f;
    if (nok) { y2v = r2[n]; biasv = bias[n]; }
    const float c = CURV_C;
    #pragma unroll
    for (int mi = 0; mi < 4; ++mi) {
        #pragma unroll
        for (int rg = 0; rg < 4; ++rg) {
            const int m = m0 + mi * 16 + lk * 4 + rg;
            const float x2 = q2[m];
            const float Bf = 1.0f - c * x2;
            const float xy = -acc[mi][rg];
            const float A  = 1.0f + 2.0f * c * xy + c * y2v;
            const float den = fmaxf(1.0f + 2.0f * c * xy + c * c * x2 * y2v, 1e-15f);
            const float num2 = A * A * x2 + 2.0f * A * Bf * xy + Bf * Bf * y2v;
            if (nok) out[(size_t)m * NREL + n] = biasv - num2 / (den * den);
        }
    }
}

extern "C" void kernel_launch(void* const* d_in, const int* in_sizes, int n_in,
                              void* d_out, int out_size, void* d_ws, size_t ws_size,
                              hipStream_t stream) {
    const float* ent  = (const float*)d_in[0];   // 20000 x 256
    const float* rel  = (const float*)d_in[1];   // 500 x 256
    const int*   trip = (const int*)d_in[2];     // 2048 x 3
    const float* grot = (const float*)d_in[3];   // 128
    const float* gref = (const float*)d_in[4];   // 128
    const float* attw = (const float*)d_in[5];   // 512
    const float* bias = (const float*)d_in[6];   // 500
    float* out = (float*)d_out;                  // 2048 x 500

    char* ws = (char*)d_ws;
    unsigned short* Qh = (unsigned short*)(ws);                       // 1 MB
    unsigned short* Ql = (unsigned short*)(ws + (1u << 20));          // 1 MB
    unsigned short* Hh = (unsigned short*)(ws + (2u << 20));          // 256 KB
    unsigned short* Hl = (unsigned short*)(ws + (2u << 20) + (256u << 10)); // 256 KB
    float* q2 = (float*)(ws + (2u << 20) + (512u << 10));             // 8 KB
    float* r2 = (float*)(ws + (2u << 20) + (512u << 10) + 8192);      // 2 KB

    const int nwaves = NRELP + BATCH;            // 2560
    prep_kernel<<<nwaves / 4, 256, 0, stream>>>(ent, rel, trip, grot, gref, attw,
                                                Qh, Ql, q2, Hh, Hl, r2);
    dim3 grid(BATCH / 64, NRELP / 64);
    score_kernel<<<grid, 256, 0, stream>>>(Qh, Ql, q2, Hh, Hl, r2, bias, out);
}

// Round 4
// 15.640 us; speedup vs baseline: 2.5443x; 1.3643x over previous
//
#include <hip/hip_runtime.h>
#include <hip/hip_bf16.h>
#include <math.h>

#define D 256
#define BATCH 2048
#define NREL 500
#define NRELP 512
#define CURV_C 0.01f
#define SQRT_C 0.1f

typedef __attribute__((ext_vector_type(8))) short s16x8;
typedef __attribute__((ext_vector_type(4))) float f32x4;

__device__ __forceinline__ float wave_reduce(float v) {
    #pragma unroll
    for (int off = 1; off < 64; off <<= 1) v += __shfl_xor(v, off, 64);
    return v;
}

__device__ __forceinline__ float dot4(float4 a, float4 b) {
    return a.x * b.x + a.y * b.y + a.z * b.z + a.w * b.w;
}

// fast tanh for x >= 0 via hardware exp
__device__ __forceinline__ float tanh_fast(float x) {
    float e = __expf(2.0f * x);
    return 1.0f - 2.0f / (e + 1.0f);
}
__device__ __forceinline__ float artanh_fast(float z) {
    z = fminf(fmaxf(z, -1.0f + 1e-7f), 1.0f - 1e-7f);
    return 0.5f * __logf((1.0f + z) / (1.0f - z));
}

__device__ __forceinline__ unsigned short f2bf(float x) {
    union { float f; unsigned int u; } c; c.f = x;
    unsigned int r = (c.u + 0x7fffu + ((c.u >> 16) & 1u)) >> 16;
    return (unsigned short)r;
}
__device__ __forceinline__ float bf2f(unsigned short h) {
    union { unsigned int u; float f; } c; c.u = ((unsigned int)h) << 16;
    return c.f;
}

__device__ __forceinline__ void store_hilo(unsigned short* ph, unsigned short* pl, float4 v) {
    ushort4 h, lo;
    #pragma unroll
    for (int e = 0; e < 4; ++e) {
        float x = (&v.x)[e];
        unsigned short hb = f2bf(x);
        float hf = bf2f(hb);
        (&h.x)[e] = hb;
        (&lo.x)[e] = f2bf(x - hf);
    }
    *(ushort4*)ph = h;
    *(ushort4*)pl = lo;
}

// ---------------- prep: wave-per-row, no barriers, fast-math trig ----------------
__global__ __launch_bounds__(256) void prep_kernel(
    const float* __restrict__ ent, const float* __restrict__ rel,
    const int* __restrict__ trip,
    const float* __restrict__ grot, const float* __restrict__ gref,
    const float* __restrict__ attw,
    unsigned short* __restrict__ Qh, unsigned short* __restrict__ Ql,
    float* __restrict__ q2out,
    unsigned short* __restrict__ Hh, unsigned short* __restrict__ Hl,
    float* __restrict__ r2out)
{
    const int w = blockIdx.x * 4 + (threadIdx.x >> 6);
    const int l = threadIdx.x & 63;

    if (w < NRELP) {
        const int r = w;
        float4 v = make_float4(0.f, 0.f, 0.f, 0.f);
        if (r < NREL) v = *(const float4*)&rel[(size_t)r * D + 4 * l];
        float n2 = wave_reduce(dot4(v, v));
        float n = fmaxf(sqrtf(n2), 1e-15f);
        float f = tanh_fast(SQRT_C * n) / (SQRT_C * n);
        float4 hv = make_float4(f * v.x, f * v.y, f * v.z, f * v.w);
        store_hilo(&Hh[(size_t)r * D + 4 * l], &Hl[(size_t)r * D + 4 * l], hv);
        if (l == 0) r2out[r] = f * f * n2;
    } else if (w < NRELP + BATCH) {
        const int b = w - NRELP;
        const int s = trip[3 * b + 0];
        const int o = trip[3 * b + 2];
        float4 se = *(const float4*)&ent[(size_t)s * D + 4 * l];
        float4 oe = *(const float4*)&ent[(size_t)o * D + 4 * l];

        float ns2 = wave_reduce(dot4(se, se));
        float no2 = wave_reduce(dot4(oe, oe));
        float ns = fmaxf(sqrtf(ns2), 1e-15f);
        float no = fmaxf(sqrtf(no2), 1e-15f);
        float fs = artanh_fast(SQRT_C * ns) / (SQRT_C * ns);
        float fo = artanh_fast(SQRT_C * no) / (SQRT_C * no);
        float4 st = make_float4(fs * se.x, fs * se.y, fs * se.z, fs * se.w);
        float4 ot = make_float4(fo * oe.x, fo * oe.y, fo * oe.z, fo * oe.w);

        float4 wa = *(const float4*)&attw[4 * l];
        float4 wb = *(const float4*)&attw[D + 4 * l];
        float adot = wave_reduce(dot4(st, wa) + dot4(ot, wb));
        float a = 1.0f / (1.0f + __expf(-adot));

        float2 ar = ((const float2*)grot)[l];
        float2 af = ((const float2*)gref)[l];
        float ca0 = __cosf(ar.x), sa0 = __sinf(ar.x);
        float ca1 = __cosf(ar.y), sa1 = __sinf(ar.y);
        float cr0 = __cosf(af.x), sr0 = __sinf(af.x);
        float cr1 = __cosf(af.y), sr1 = __sinf(af.y);

        float4 rot = make_float4(ca0 * st.x - sa0 * st.y, sa0 * st.x + ca0 * st.y,
                                 ca1 * st.z - sa1 * st.w, sa1 * st.z + ca1 * st.w);
        float4 rfl = make_float4(cr0 * st.x + sr0 * st.y, sr0 * st.x - cr0 * st.y,
                                 cr1 * st.z + sr1 * st.w, sr1 * st.z - cr1 * st.w);
        float ia = 1.0f - a;
        float4 mt = make_float4(a * rot.x + ia * rfl.x, a * rot.y + ia * rfl.y,
                                a * rot.z + ia * rfl.z, a * rot.w + ia * rfl.w);

        float nm2 = wave_reduce(dot4(mt, mt));
        float nm = fmaxf(sqrtf(nm2), 1e-15f);
        float fm = tanh_fast(SQRT_C * nm) / (SQRT_C * nm);
        float4 mh = make_float4(fm * mt.x, fm * mt.y, fm * mt.z, fm * mt.w);
        float x2v = fm * fm * nm2;

        float xy = wave_reduce(-dot4(mh, oe));
        const float c = CURV_C;
        float A  = 1.0f + 2.0f * c * xy + c * no2;
        float Bf = 1.0f - c * x2v;
        float den = fmaxf(1.0f + 2.0f * c * xy + c * c * x2v * no2, 1e-15f);
        float inv = 1.0f / den;
        float4 q = make_float4((A * -mh.x + Bf * oe.x) * inv,
                               (A * -mh.y + Bf * oe.y) * inv,
                               (A * -mh.z + Bf * oe.z) * inv,
                               (A * -mh.w + Bf * oe.w) * inv);
        store_hilo(&Qh[(size_t)b * D + 4 * l], &Ql[(size_t)b * D + 4 * l], q);
        if (l == 0) {
            float num2 = A * A * x2v + 2.0f * A * Bf * xy + Bf * Bf * no2;
            q2out[b] = num2 * inv * inv;
        }
    }
}

// ---------------- score: 64x64 tile, 8 waves, MFMA bf16 hi/lo ----------------
// LDS: Ah @0, Al @32768, Bh @65536, Bl @98304; each [64 rows][256 k] bf16, 512B/row.
// Storage rule: LDS[row][chunk c] holds global 16B-chunk (c ^ (row&7)) of that row.
// Staged via global_load_lds (linear LDS dest, pre-swizzled global source).
__global__ __launch_bounds__(512) void score_kernel(
    const unsigned short* __restrict__ Qh, const unsigned short* __restrict__ Ql,
    const float* __restrict__ q2,
    const unsigned short* __restrict__ Hh, const unsigned short* __restrict__ Hl,
    const float* __restrict__ r2,
    const float* __restrict__ bias, float* __restrict__ out)
{
    __shared__ __align__(16) unsigned char lds[131072];
    const int t = threadIdx.x;
    const int m0 = blockIdx.x * 64, n0 = blockIdx.y * 64;
    const int w = t >> 6;            // wave 0..7
    const int l = t & 63;

    // ---- stage: each wave fills rows [w*8, w*8+8) of all four 32KB arrays.
    // LDS linear addr (per array) = w*4096 + it*1024 + lane*16
    //   -> row = w*8 + it*2 + (lane>>5), chunk = lane&31
    {
        const int rsub = l >> 5;         // 0,1
        const int cl = l & 31;
        #pragma unroll
        for (int it = 0; it < 4; ++it) {
            const int r = w * 8 + it * 2 + rsub;
            const unsigned int csw = (unsigned int)((cl ^ (r & 7)) * 8); // elem offset
            const unsigned int loff = (unsigned int)(w * 4096 + it * 1024);
            const size_t gA = (size_t)(m0 + r) * D + csw;
            const size_t gB = (size_t)(n0 + r) * D + csw;
            __builtin_amdgcn_global_load_lds(
                (const __attribute__((address_space(1))) void*)(Qh + gA),
                (__attribute__((address_space(3))) void*)(lds + loff), 16, 0, 0);
            __builtin_amdgcn_global_load_lds(
                (const __attribute__((address_space(1))) void*)(Ql + gA),
                (__attribute__((address_space(3))) void*)(lds + 32768 + loff), 16, 0, 0);
            __builtin_amdgcn_global_load_lds(
                (const __attribute__((address_space(1))) void*)(Hh + gB),
                (__attribute__((address_space(3))) void*)(lds + 65536 + loff), 16, 0, 0);
            __builtin_amdgcn_global_load_lds(
                (const __attribute__((address_space(1))) void*)(Hl + gB),
                (__attribute__((address_space(3))) void*)(lds + 98304 + loff), 16, 0, 0);
        }
    }
    __syncthreads();

    // ---- MFMA: wave (wm, wn) owns m-strip [wm*32, wm*32+32) x n-strip [wn*16, wn*16+16)
    const int wm = w >> 2;           // 0,1
    const int wn = w & 3;            // 0..3
    const int lr = l & 15;
    const int lk = l >> 4;           // 0..3
    const unsigned int sw = (unsigned int)((lr & 7) << 4);

    f32x4 acc[2];
    acc[0] = (f32x4){0.f, 0.f, 0.f, 0.f};
    acc[1] = (f32x4){0.f, 0.f, 0.f, 0.f};

    const unsigned int bbase = (unsigned int)((wn * 16 + lr) * 512);
    const unsigned int abase = (unsigned int)((wm * 32 + lr) * 512);
    #pragma unroll
    for (int ks = 0; ks < 8; ++ks) {
        const unsigned int coff = ((unsigned int)(ks * 4 + lk) << 4) ^ sw;
        s16x8 bh = *(const s16x8*)(lds + 65536 + bbase + coff);
        s16x8 bl = *(const s16x8*)(lds + 98304 + bbase + coff);
        #pragma unroll
        for (int mi = 0; mi < 2; ++mi) {
            const unsigned int aoff = abase + (unsigned int)(mi * 16 * 512) + coff;
            s16x8 ah = *(const s16x8*)(lds + aoff);
            s16x8 al = *(const s16x8*)(lds + 32768 + aoff);
            acc[mi] = __builtin_amdgcn_mfma_f32_16x16x32_bf16(ah, bh, acc[mi], 0, 0, 0);
            acc[mi] = __builtin_amdgcn_mfma_f32_16x16x32_bf16(ah, bl, acc[mi], 0, 0, 0);
            acc[mi] = __builtin_amdgcn_mfma_f32_16x16x32_bf16(al, bh, acc[mi], 0, 0, 0);
        }
    }

    // ---- epilogue: C layout col(n)=lane&15, row(m)=(lane>>4)*4+reg
    const int n = n0 + wn * 16 + lr;
    const bool nok = (n < NREL);
    float y2v = 0.f, biasv = 0.f;
    if (nok) { y2v = r2[n]; biasv = bias[n]; }
    const float c = CURV_C;
    #pragma unroll
    for (int mi = 0; mi < 2; ++mi) {
        #pragma unroll
        for (int rg = 0; rg < 4; ++rg) {
            const int m = m0 + wm * 32 + mi * 16 + lk * 4 + rg;
            const float x2 = q2[m];
            const float Bf = 1.0f - c * x2;
            const float xy = -acc[mi][rg];
            const float A  = 1.0f + 2.0f * c * xy + c * y2v;
            const float den = fmaxf(1.0f + 2.0f * c * xy + c * c * x2 * y2v, 1e-15f);
            const float num2 = A * A * x2 + 2.0f * A * Bf * xy + Bf * Bf * y2v;
            if (nok) out[(size_t)m * NREL + n] = biasv - num2 / (den * den);
        }
    }
}

extern "C" void kernel_launch(void* const* d_in, const int* in_sizes, int n_in,
                              void* d_out, int out_size, void* d_ws, size_t ws_size,
                              hipStream_t stream) {
    const float* ent  = (const float*)d_in[0];   // 20000 x 256
    const float* rel  = (const float*)d_in[1];   // 500 x 256
    const int*   trip = (const int*)d_in[2];     // 2048 x 3
    const float* grot = (const float*)d_in[3];   // 128
    const float* gref = (const float*)d_in[4];   // 128
    const float* attw = (const float*)d_in[5];   // 512
    const float* bias = (const float*)d_in[6];   // 500
    float* out = (float*)d_out;                  // 2048 x 500

    char* ws = (char*)d_ws;
    unsigned short* Qh = (unsigned short*)(ws);                       // 1 MB
    unsigned short* Ql = (unsigned short*)(ws + (1u << 20));          // 1 MB
    unsigned short* Hh = (unsigned short*)(ws + (2u << 20));          // 256 KB
    unsigned short* Hl = (unsigned short*)(ws + (2u << 20) + (256u << 10)); // 256 KB
    float* q2 = (float*)(ws + (2u << 20) + (512u << 10));             // 8 KB
    float* r2 = (float*)(ws + (2u << 20) + (512u << 10) + 8192);      // 2 KB

    const int nwaves = NRELP + BATCH;            // 2560
    prep_kernel<<<nwaves / 4, 256, 0, stream>>>(ent, rel, trip, grot, gref, attw,
                                                Qh, Ql, q2, Hh, Hl, r2);
    dim3 grid(BATCH / 64, NRELP / 64);
    score_kernel<<<grid, 512, 0, stream>>>(Qh, Ql, q2, Hh, Hl, r2, bias, out);
}